// Round 7
// baseline (276.670 us; speedup 1.0000x reference)
//
#include <hip/hip_runtime.h>
#include <math.h>

#define EMB 256
#define DR  128   // resource feature dim
#define DO  192   // operation feature dim
#define DE  64    // edge_attr dim
#define RPB 8     // resources per block in k_h
#define FRPB 16   // resources per block in k_final (32 spills acc, R5 post-mortem)
#define KV_CH 8   // k-rows per block in the v part of k_prep
#define HB 256    // histogram blocks in k_prep
#define UB 8      // edges in flight per wave in k_gather

__device__ __forceinline__ float leaky(float x) { return x >= 0.f ? x : 0.2f * x; }

// Fused prep: blocks [0,128) transpose W_self -> wsT [128][256];
// blocks [128,384) transpose W_op -> wT [256][256];
// blocks [384,416) accumulate v[j] = sum_k W_op[k][j]*a_op[256+k] (v pre-zeroed);
// blocks [416,416+HB) histogram edge_dst into counts (pre-zeroed).
__global__ void k_prep(float* __restrict__ wsT, float* __restrict__ wT,
                       float* __restrict__ v, const float* __restrict__ W_self,
                       const float* __restrict__ W_op, const float* __restrict__ a_op,
                       const int* __restrict__ edst, int* __restrict__ counts, int E) {
    int b = blockIdx.x, t = threadIdx.x;
    if (b < 128) {
        int i = b * 256 + t;
        int k = i & 255, j = i >> 8;    // wsT[j*256+k] = W_self[k*128+j]
        wsT[i] = W_self[k * DR + j];
    } else if (b < 384) {
        int i = (b - 128) * 256 + t;
        int k = i & 255, j = i >> 8;    // wT[j*256+k] = W_op[k*256+j]
        wT[i] = W_op[(size_t)k * EMB + j];
    } else if (b < 416) {
        int k0 = (b - 384) * KV_CH;
        float acc = 0.f;
#pragma unroll
        for (int u = 0; u < KV_CH; u++)
            acc += W_op[(size_t)(k0 + u) * EMB + t] * a_op[EMB + k0 + u];
        atomicAdd(&v[t], acc);
    } else {
        int i = (b - 416) * 256 + t;
        int n = HB * 256;
        for (int e = i; e < E; e += n) atomicAdd(&counts[edst[e]], 1);
    }
}

// h[r] = resources[r] @ wsT, plus per-resource scores:
// tcross[r] = h[r]·a_op[:256], p_self[r] = exp(leaky(h[r]·(a_self[:256]+a_self[256:]))).
__global__ void k_h(const float* __restrict__ res, const float* __restrict__ wsT,
                    const float* __restrict__ a_self, const float* __restrict__ a_op,
                    float* __restrict__ h, float* __restrict__ tcross,
                    float* __restrict__ p_self, int R) {
    __shared__ float rrow[RPB][DR];
    __shared__ float hred[RPB][4][2];
    int r0 = blockIdx.x * RPB;
    int k = threadIdx.x;
    int w = k >> 6, l = k & 63;
    for (int i = k; i < RPB * DR; i += EMB) {
        int rr = i / DR, j = i % DR;
        rrow[rr][j] = (r0 + rr < R) ? res[(size_t)(r0 + rr) * DR + j] : 0.f;
    }
    __syncthreads();
    float acc[RPB];
#pragma unroll
    for (int rr = 0; rr < RPB; rr++) acc[rr] = 0.f;
    for (int j = 0; j < DR; j++) {
        float wv = wsT[j * EMB + k];
#pragma unroll
        for (int rr = 0; rr < RPB; rr++) acc[rr] += rrow[rr][j] * wv;
    }
    float as_ = a_self[k] + a_self[EMB + k];
    float ao_ = a_op[k];
#pragma unroll
    for (int rr = 0; rr < RPB; rr++) {
        if (r0 + rr < R) h[(size_t)(r0 + rr) * EMB + k] = acc[rr];
        float s1 = acc[rr] * as_;
        float s2 = acc[rr] * ao_;
        for (int m = 1; m < 64; m <<= 1) {
            s1 += __shfl_xor(s1, m, 64);
            s2 += __shfl_xor(s2, m, 64);
        }
        if (l == 0) { hred[rr][w][0] = s1; hred[rr][w][1] = s2; }
    }
    __syncthreads();
    if (k < RPB) {
        int r = r0 + k;
        if (r < R) {
            float a1 = hred[k][0][0] + hred[k][1][0] + hred[k][2][0] + hred[k][3][0];
            float a2 = hred[k][0][1] + hred[k][1][1] + hred[k][2][1] + hred[k][3][1];
            p_self[r] = expf(leaky(a1));
            tcross[r] = a2;
        }
    }
}

// single block: exclusive scan of counts -> offs (R+1) and cursor copy.
__global__ void k_scan(const int* __restrict__ counts, int* __restrict__ offs,
                       int* __restrict__ cursor, int R) {
    __shared__ int ps[1024];
    int tid = threadIdx.x;
    int chunk = (R + 1023) >> 10;
    int start = tid * chunk;
    int end = min(start + chunk, R);
    int s = 0;
    for (int i = start; i < end; i++) s += counts[i];
    ps[tid] = s;
    __syncthreads();
    for (int off = 1; off < 1024; off <<= 1) {
        int add = (tid >= off) ? ps[tid - off] : 0;
        __syncthreads();
        ps[tid] += add;
        __syncthreads();
    }
    int run = ps[tid] - s;
    for (int i = start; i < end; i++) {
        offs[i] = run;
        cursor[i] = run;
        run += counts[i];
    }
    if (tid == 0) offs[R] = ps[1023];
}

// scatter edges into CSR order; meta = {src, e} (8B).
__global__ void k_scatter(const int* __restrict__ edst, const int* __restrict__ esrc,
                          int* __restrict__ cursor, int2* __restrict__ meta, int E) {
    int i = blockIdx.x * blockDim.x + threadIdx.x;
    int n = gridDim.x * blockDim.x;
    for (int e = i; e < E; e += n) {
        int pos = atomicAdd(&cursor[edst[e]], 1);
        meta[pos] = make_int2(esrc[e], e);
    }
}

// One resource per WAVE (4 per block), no LDS, no block barriers.
// Lane l owns concat column group l*4..l*4+3 (l<48 -> ops cols, l>=48 -> ea cols);
// one edge's full 1KB concat row is loaded by one wave-wide float4 load.
// Per edge: d = full-wave xor-reduce of per-lane dot = concat(ops[src],ea[e])·v
// (covers s_op AND the ea part -> no precomputed s_op needed);
// p = exp(leaky(tcross[r] + d)); acc(lane cols) += p*row; ps += p (every lane
// sees every edge -> psum needs no reduce). UB=8 edges in flight per wave.
__global__ __launch_bounds__(256, 4) void k_gather(
        const float* __restrict__ ops, const float* __restrict__ ea,
        const int2* __restrict__ meta, const int* __restrict__ offs,
        const float* __restrict__ v, const float* __restrict__ tcross,
        float* __restrict__ X, float* __restrict__ psum, int R) {
    int t = threadIdx.x;
    int w = t >> 6, l = t & 63;
    int r = blockIdx.x * 4 + w;
    if (r >= R) return;
    int beg = offs[r], end = offs[r + 1], cnt = end - beg;
    float tc = tcross[r];
    float4 vv = *(const float4*)(v + l * 4);          // concat-space v slice
    const float* tbl = (l < 48) ? ops : ea;
    const int lo = (l < 48) ? l * 4 : (l - 48) * 4;   // within-row float offset
    float4 acc = {0.f, 0.f, 0.f, 0.f};
    float ps = 0.f;
    for (int base = 0; base < cnt; base += 64) {
        int n = min(64, cnt - base);
        int o1 = 0, o2 = 0;
        if (l < n) {
            int2 mm = meta[beg + base + l];
            o1 = mm.x * DO;   // float offset of ops row
            o2 = mm.y * DE;   // float offset of ea row
        }
        for (int jb = 0; jb < n; jb += UB) {
            float4 ld[UB];
            float d[UB];
#pragma unroll
            for (int k = 0; k < UB; k++) {
                int j = jb + k;
                int jj = (j < n) ? j : 0;
                int u1 = __shfl(o1, jj, 64);
                int u2 = __shfl(o2, jj, 64);
                int off = (l < 48) ? u1 : u2;
                ld[k] = *(const float4*)(tbl + (size_t)off + lo);
            }
#pragma unroll
            for (int k = 0; k < UB; k++)
                d[k] = ld[k].x * vv.x + ld[k].y * vv.y + ld[k].z * vv.z + ld[k].w * vv.w;
#pragma unroll
            for (int m = 1; m < 64; m <<= 1) {
#pragma unroll
                for (int k = 0; k < UB; k++) d[k] += __shfl_xor(d[k], m, 64);
            }
#pragma unroll
            for (int k = 0; k < UB; k++) {
                float sc = tc + d[k];
                float p = expf(sc >= 0.f ? sc : 0.2f * sc);
                p = (jb + k < n) ? p : 0.f;
                ps += p;
                acc.x += p * ld[k].x; acc.y += p * ld[k].y;
                acc.z += p * ld[k].z; acc.w += p * ld[k].w;
            }
        }
    }
    *(float4*)(X + (size_t)r * EMB + l * 4) = acc;  // full-wave 1KB row store
    if (l == 0) psum[r] = ps;
}

// S = sum(p_self) + sum(psum)
__global__ void k_sum(const float* __restrict__ p_self, const float* __restrict__ psum,
                      int R, float* __restrict__ S) {
    __shared__ float fs[1024];
    int t = threadIdx.x;
    float fv = 0.f;
    for (int i = t; i < R; i += 1024) fv += p_self[i] + psum[i];
    fs[t] = fv;
    __syncthreads();
    for (int off = 512; off > 0; off >>= 1) {
        if (t < off) fs[t] += fs[t + off];
        __syncthreads();
    }
    if (t == 0) *S = fs[0];
}

// out[r][c] = elu( (p_self[r]*h[r][c] + sum_j wT[j][c]*X[r][j]) / S )
__global__ void k_final(const float* __restrict__ X, const float* __restrict__ wT,
                        const float* __restrict__ h, const float* __restrict__ p_self,
                        const float* __restrict__ Sp, float* __restrict__ out, int R) {
    __shared__ float xl[FRPB][EMB];
    __shared__ float ps[FRPB];
    int r0 = blockIdx.x * FRPB;
    int t = threadIdx.x;
    for (int idx = t; idx < FRPB * EMB / 4; idx += 256) {
        int rr = idx >> 6;  // 64 float4 per row
        float4 val = (r0 + rr < R) ? ((const float4*)(X + (size_t)r0 * EMB))[idx]
                                   : make_float4(0.f, 0.f, 0.f, 0.f);
        ((float4*)xl)[idx] = val;
    }
    if (t < FRPB) ps[t] = (r0 + t < R) ? p_self[r0 + t] : 0.f;
    __syncthreads();
    float acc[FRPB];
#pragma unroll
    for (int rr = 0; rr < FRPB; rr++) acc[rr] = 0.f;
    int c = t;
    for (int j = 0; j < EMB; j += 4) {
        float w0 = wT[(j + 0) * EMB + c];
        float w1 = wT[(j + 1) * EMB + c];
        float w2 = wT[(j + 2) * EMB + c];
        float w3 = wT[(j + 3) * EMB + c];
#pragma unroll
        for (int rr = 0; rr < FRPB; rr++) {
            float4 xv = *(const float4*)&xl[rr][j];
            acc[rr] += xv.x * w0 + xv.y * w1 + xv.z * w2 + xv.w * w3;
        }
    }
    float inv = 1.f / (*Sp);
#pragma unroll
    for (int rr = 0; rr < FRPB; rr++) {
        int r = r0 + rr;
        if (r < R) {
            float val = (ps[rr] * h[(size_t)r * EMB + c] + acc[rr]) * inv;
            out[(size_t)r * EMB + c] = val > 0.f ? val : expm1f(val);
        }
    }
}

extern "C" void kernel_launch(void* const* d_in, const int* in_sizes, int n_in,
                              void* d_out, int out_size, void* d_ws, size_t ws_size,
                              hipStream_t stream) {
    const float* resources = (const float*)d_in[0];
    const float* operations = (const float*)d_in[1];
    const float* edge_attr = (const float*)d_in[2];
    const float* W_self = (const float*)d_in[3];
    const float* W_op = (const float*)d_in[4];
    const float* a_self = (const float*)d_in[5];
    const float* a_op = (const float*)d_in[6];
    const int* edge_src = (const int*)d_in[7];
    const int* edge_dst = (const int*)d_in[8];
    float* out = (float*)d_out;

    const int R = in_sizes[0] / DR;
    const int E = in_sizes[2] / DE;

    // workspace carve — counts and v first so one memset zeroes both
    int* counts = (int*)d_ws;                 // R
    float* v = (float*)(counts + R);          // 256
    float* wsT = v + EMB;                     // 128*256
    float* wT = wsT + DR * EMB;               // 256*256
    float* h = wT + EMB * EMB;                // R*256
    float* X = h + (size_t)R * EMB;           // R*256
    float* tcross = X + (size_t)R * EMB;      // R
    float* p_self = tcross + R;               // R
    float* psum = p_self + R;                 // R
    float* S = psum + R;                      // 1
    int* offs = (int*)(S + 1);                // R+1
    int* cursor = offs + R + 1;               // R
    int2* meta = (int2*)(cursor + R);         // E (8B each)

    hipMemsetAsync(d_ws, 0, (size_t)(R + EMB) * sizeof(float), stream);

    k_prep<<<416 + HB, 256, 0, stream>>>(wsT, wT, v, W_self, W_op, a_op, edge_dst,
                                         counts, E);
    k_h<<<(R + RPB - 1) / RPB, EMB, 0, stream>>>(resources, wsT, a_self, a_op, h,
                                                 tcross, p_self, R);
    k_scan<<<1, 1024, 0, stream>>>(counts, offs, cursor, R);
    k_scatter<<<1024, 256, 0, stream>>>(edge_dst, edge_src, cursor, meta, E);
    k_gather<<<(R + 3) / 4, 256, 0, stream>>>(operations, edge_attr, meta, offs, v,
                                              tcross, X, psum, R);
    k_sum<<<1, 1024, 0, stream>>>(p_self, psum, R, S);
    k_final<<<(R + FRPB - 1) / FRPB, 256, 0, stream>>>(X, wT, h, p_self, S, out, R);
}